// Round 5
// baseline (3853.038 us; speedup 1.0000x reference)
//
#include <hip/hip_runtime.h>
#include <stdint.h>

#define B_    4096
#define H_    1024
#define T_    60
#define IN_   1028
#define KA_   1056      // IN_ padded to multiple of 32
#define G4_   4096      // 4*H
#define MLPH_ 64
#define NB_   6         // MLP batch depth / h ring size

typedef __attribute__((ext_vector_type(8))) short bf16x8;
typedef __attribute__((ext_vector_type(4))) float f32x4;
typedef __attribute__((ext_vector_type(4))) unsigned short u16x4;

#define GLOBAL_AS __attribute__((address_space(1)))
#define LDS_AS    __attribute__((address_space(3)))

__device__ __forceinline__ void gload_lds16(const void* g, void* l) {
  __builtin_amdgcn_global_load_lds((GLOBAL_AS void*)const_cast<void*>(g),
                                   (LDS_AS void*)l, 16, 0, 0);
}

__device__ __forceinline__ unsigned short f2bf(float f) {
  union { float f; unsigned int u; } v; v.f = f;
  unsigned int r = v.u + 0x7FFFu + ((v.u >> 16) & 1u);
  return (unsigned short)(r >> 16);
}

__device__ __forceinline__ float bf2f(unsigned short u) {
  union { unsigned int u; float f; } v; v.u = ((unsigned int)u) << 16;
  return v.f;
}

__device__ __forceinline__ float sigmf(float x) {
  float e = __expf(-x);
  return __builtin_amdgcn_rcpf(1.0f + e);
}

__device__ __forceinline__ float tanh_fast(float x) {
  x = fminf(fmaxf(x, -15.0f), 15.0f);
  float e = __expf(2.0f * x);
  return (e - 1.0f) * __builtin_amdgcn_rcpf(e + 1.0f);
}

// ---------------- conversion / setup kernels ----------------

__global__ void k_conv_bf16(const float* __restrict__ src,
                            unsigned short* __restrict__ dst, int n) {
  int i = blockIdx.x * blockDim.x + threadIdx.x;
  int stride = gridDim.x * blockDim.x;
  for (; i < n; i += stride) dst[i] = f2bf(src[i]);
}

// W_ih (4096 x 1028) -> bf16 padded (4096 x 1056)
__global__ void k_conv_wih(const float* __restrict__ w,
                           unsigned short* __restrict__ dst) {
  int i = blockIdx.x * blockDim.x + threadIdx.x;
  int stride = gridDim.x * blockDim.x;
  const int n = G4_ * KA_;
  for (; i < n; i += stride) {
    int r = i / KA_, k = i - r * KA_;
    dst[i] = (k < IN_) ? f2bf(w[(size_t)r * IN_ + k]) : (unsigned short)0;
  }
}

// z_aug = [z | last_pos | last_vel | zero-pad]  (4096 x 1056 bf16)
__global__ void k_build_zaug(const float* __restrict__ z,
                             const float* __restrict__ lp,
                             const float* __restrict__ lv,
                             unsigned short* __restrict__ dst) {
  int i = blockIdx.x * blockDim.x + threadIdx.x;
  int stride = gridDim.x * blockDim.x;
  const int n = B_ * KA_;
  for (; i < n; i += stride) {
    int b = i / KA_, k = i - b * KA_;
    float v;
    if (k < H_)            v = z[(size_t)b * H_ + k];
    else if (k < H_ + 2)   v = lp[b * 2 + (k - H_)];
    else if (k < IN_)      v = lv[b * 2 + (k - H_ - 2)];
    else                   v = 0.0f;
    dst[i] = f2bf(v);
  }
}

// LDS swizzle: chunk = 16 rows x 64B (1KB). gload_lds writes lane l -> l*16 (linear).
// Source pre-swizzle: lane l loads global slot (l&3)^((l>>3)&3) of row l>>2.
// Read swizzle: element (row R, slot S) lives at R*64 + (S^((R>>1)&3))*16.

// ---------------- x_gates GEMM -> interleaved bf16x4 per (b, hc) ----------------
// (round-3 structure: 2-buffer, syncthreads; runs once — not the hot kernel)

__global__ __launch_bounds__(256, 4) void k_xgates(
    const unsigned short* __restrict__ zaug, const unsigned short* __restrict__ wih,
    const float* __restrict__ bih, const float* __restrict__ bhh,
    u16x4* __restrict__ xg4) {
  __shared__ unsigned short As[2][128 * 32];
  __shared__ unsigned short Bs[2][128 * 32];
  const int tid = threadIdx.x, lane = tid & 63, wave = tid >> 6;
  const int bx = blockIdx.x, by = blockIdx.y;
  const int wm = wave >> 1, wn = wave & 1;
  const int rs = lane >> 2;
  const int c16 = (((lane & 3) ^ ((lane >> 3) & 3))) * 16;
  const int rdslot = ((lane >> 4) ^ ((lane >> 1) & 3)) * 8;

  const char* asrc0 = (const char*)zaug + ((size_t)(bx * 128 + (wave * 2 + 0) * 16 + rs) * KA_) * 2 + c16;
  const char* asrc1 = (const char*)zaug + ((size_t)(bx * 128 + (wave * 2 + 1) * 16 + rs) * KA_) * 2 + c16;
  const char* bsrc0 = (const char*)wih  + ((size_t)(wave * H_ + by * 32 +  0 + rs) * KA_) * 2 + c16;
  const char* bsrc1 = (const char*)wih  + ((size_t)(wave * H_ + by * 32 + 16 + rs) * KA_) * 2 + c16;

  f32x4 acc[4][4];   // [gate][m]
#pragma unroll
  for (int g = 0; g < 4; ++g)
#pragma unroll
    for (int m = 0; m < 4; ++m) acc[g][m] = {0.f, 0.f, 0.f, 0.f};

  gload_lds16(asrc0, &As[0][(wave * 2 + 0) * 512]);
  gload_lds16(asrc1, &As[0][(wave * 2 + 1) * 512]);
  gload_lds16(bsrc0, &Bs[0][(wave * 2 + 0) * 512]);
  gload_lds16(bsrc1, &Bs[0][(wave * 2 + 1) * 512]);
  __syncthreads();

  const int nt = KA_ / 32;
  int cur = 0;
  for (int kk = 0; kk < nt; ++kk) {
    if (kk + 1 < nt) {
      const size_t kb = (size_t)(kk + 1) * 64;
      gload_lds16(asrc0 + kb, &As[cur ^ 1][(wave * 2 + 0) * 512]);
      gload_lds16(asrc1 + kb, &As[cur ^ 1][(wave * 2 + 1) * 512]);
      gload_lds16(bsrc0 + kb, &Bs[cur ^ 1][(wave * 2 + 0) * 512]);
      gload_lds16(bsrc1 + kb, &Bs[cur ^ 1][(wave * 2 + 1) * 512]);
    }
    bf16x8 a[4], b[4];
#pragma unroll
    for (int m = 0; m < 4; ++m)
      a[m] = *(const bf16x8*)&As[cur][(wm * 64 + m * 16 + (lane & 15)) * 32 + rdslot];
#pragma unroll
    for (int g = 0; g < 4; ++g)
      b[g] = *(const bf16x8*)&Bs[cur][((g * 2 + wn) * 16 + (lane & 15)) * 32 + rdslot];
#pragma unroll
    for (int g = 0; g < 4; ++g)
#pragma unroll
      for (int m = 0; m < 4; ++m)
        acc[g][m] = __builtin_amdgcn_mfma_f32_16x16x32_bf16(a[m], b[g], acc[g][m], 0, 0, 0);
    __syncthreads();
    cur ^= 1;
  }

  const int r0 = (lane >> 4) * 4, cl = lane & 15;
  const int hc = by * 32 + wn * 16 + cl;
  const float bi = bih[hc]        + bhh[hc];
  const float bf = bih[1024 + hc] + bhh[1024 + hc];
  const float bg = bih[2048 + hc] + bhh[2048 + hc];
  const float bo = bih[3072 + hc] + bhh[3072 + hc];
#pragma unroll
  for (int m = 0; m < 4; ++m)
#pragma unroll
    for (int j = 0; j < 4; ++j) {
      int row = bx * 128 + wm * 64 + m * 16 + r0 + j;
      u16x4 st = {f2bf(acc[0][m][j] + bi), f2bf(acc[1][m][j] + bf),
                  f2bf(acc[2][m][j] + bg), f2bf(acc[3][m][j] + bo)};
      xg4[(size_t)row * H_ + hc] = st;
    }
}

// ---------------- LSTM step: gates = xg + h @ W_hh^T, fused cell update ----------------
// 3-buffer LDS, depth-2 prefetch, raw s_barrier + counted vmcnt (T3+T4).
// Ledger (per wave, 4 gloads/tile): steady state 8 outstanding; vmcnt(4) at top
// retires the current tile. Peeled iters 30/31 fold in epilogue prefetch:
// iter30: vmcnt(4), +16 xg4 loads -> 20 in flight; iter31: vmcnt(16) (t31 done),
// +16 cbuf loads; epilogue auto-waits.

__global__ __launch_bounds__(256, 3) void k_step(
    const unsigned short* __restrict__ hprev, const unsigned short* __restrict__ whh,
    const u16x4* __restrict__ xg4, float* __restrict__ cbuf,
    unsigned short* __restrict__ hout) {
  __shared__ unsigned short As[3][128 * 32];
  __shared__ unsigned short Bs[3][128 * 32];
  const int tid = threadIdx.x, lane = tid & 63, wave = tid >> 6;
  const int bx = blockIdx.x, by = blockIdx.y;
  const int wm = wave >> 1, wn = wave & 1;
  const int rs = lane >> 2;
  const int c16 = (((lane & 3) ^ ((lane >> 3) & 3))) * 16;
  const int rdslot = ((lane >> 4) ^ ((lane >> 1) & 3)) * 8;

  const char* asrc0 = (const char*)hprev + ((size_t)(bx * 128 + (wave * 2 + 0) * 16 + rs) * H_) * 2 + c16;
  const char* asrc1 = (const char*)hprev + ((size_t)(bx * 128 + (wave * 2 + 1) * 16 + rs) * H_) * 2 + c16;
  const char* bsrc0 = (const char*)whh   + ((size_t)(wave * H_ + by * 32 +  0 + rs) * H_) * 2 + c16;
  const char* bsrc1 = (const char*)whh   + ((size_t)(wave * H_ + by * 32 + 16 + rs) * H_) * 2 + c16;

  f32x4 acc[4][4];   // [gate][m]
#pragma unroll
  for (int g = 0; g < 4; ++g)
#pragma unroll
    for (int m = 0; m < 4; ++m) acc[g][m] = {0.f, 0.f, 0.f, 0.f};

  auto stage = [&](int t, int bi) {
    const size_t kb = (size_t)t * 64;
    gload_lds16(asrc0 + kb, &As[bi][(wave * 2 + 0) * 512]);
    gload_lds16(asrc1 + kb, &As[bi][(wave * 2 + 1) * 512]);
    gload_lds16(bsrc0 + kb, &Bs[bi][(wave * 2 + 0) * 512]);
    gload_lds16(bsrc1 + kb, &Bs[bi][(wave * 2 + 1) * 512]);
  };

  auto compute = [&](int bi) {
    bf16x8 a[4], b[4];
#pragma unroll
    for (int m = 0; m < 4; ++m)
      a[m] = *(const bf16x8*)&As[bi][(wm * 64 + m * 16 + (lane & 15)) * 32 + rdslot];
#pragma unroll
    for (int g = 0; g < 4; ++g)
      b[g] = *(const bf16x8*)&Bs[bi][((g * 2 + wn) * 16 + (lane & 15)) * 32 + rdslot];
#pragma unroll
    for (int g = 0; g < 4; ++g)
#pragma unroll
      for (int m = 0; m < 4; ++m)
        acc[g][m] = __builtin_amdgcn_mfma_f32_16x16x32_bf16(a[m], b[g], acc[g][m], 0, 0, 0);
  };

  // prologue: 2 tiles in flight (8 loads/wave)
  stage(0, 0);
  stage(1, 1);

  // main loop: tiles 0..29 (nt = 32)
  int cur = 0;
  for (int kk = 0; kk < 30; ++kk) {
    asm volatile("s_waitcnt vmcnt(4)" ::: "memory");   // own tile-kk loads done
    __builtin_amdgcn_s_barrier();                      // all waves' tile-kk done
    int nb = cur + 2; if (nb >= 3) nb -= 3;
    stage(kk + 2, nb);                                 // back to 8 in flight
    compute(cur);
    ++cur; if (cur == 3) cur = 0;
  }

  const int r0 = (lane >> 4) * 4, cl = lane & 15;
  const int hc = by * 32 + wn * 16 + cl;
  const int browbase = bx * 128 + wm * 64 + r0;

  // tile 30 (in buf 0): issue xg4 epilogue prefetch (16 loads)
  asm volatile("s_waitcnt vmcnt(4)" ::: "memory");
  __builtin_amdgcn_s_barrier();
  u16x4 xpre[4][4];
#pragma unroll
  for (int m = 0; m < 4; ++m)
#pragma unroll
    for (int j = 0; j < 4; ++j)
      xpre[m][j] = xg4[(size_t)(browbase + m * 16 + j) * H_ + hc];
  compute(0);

  // tile 31 (in buf 1): 4 t31-loads are oldest, then 16 xg4 -> vmcnt(16)
  asm volatile("s_waitcnt vmcnt(16)" ::: "memory");
  __builtin_amdgcn_s_barrier();
  float cpre[4][4];
#pragma unroll
  for (int m = 0; m < 4; ++m)
#pragma unroll
    for (int j = 0; j < 4; ++j)
      cpre[m][j] = cbuf[(size_t)(browbase + m * 16 + j) * H_ + hc];
  compute(1);

  // epilogue (compiler inserts waits for xpre/cpre uses)
#pragma unroll
  for (int m = 0; m < 4; ++m)
#pragma unroll
    for (int j = 0; j < 4; ++j) {
      size_t ci = (size_t)(browbase + m * 16 + j) * H_ + hc;
      u16x4 xv = xpre[m][j];
      float iv = sigmf(acc[0][m][j] + bf2f(xv[0]));
      float fv = sigmf(acc[1][m][j] + bf2f(xv[1]));
      float gv = tanh_fast(acc[2][m][j] + bf2f(xv[2]));
      float ov = sigmf(acc[3][m][j] + bf2f(xv[3]));
      float cv = fv * cpre[m][j] + iv * gv;
      cbuf[ci] = cv;
      hout[ci] = f2bf(ov * tanh_fast(cv));
    }
}

// ---------------- batched MLP over NB_ steps ----------------

__global__ __launch_bounds__(256) void k_mlp(
    const unsigned short* __restrict__ hring, const unsigned short* __restrict__ w1,
    const float* __restrict__ b1, const float* __restrict__ w2,
    const float* __restrict__ b2, float* __restrict__ delta, int t0) {
  __shared__ unsigned short As[64 * 32];
  __shared__ unsigned short Bs[64 * 32];
  __shared__ float hid[64][65];
  const int tid = threadIdx.x, lane = tid & 63, wave = tid >> 6;
  const int bx = blockIdx.x;
  const unsigned short* h = hring + (size_t)blockIdx.y * B_ * H_;
  const int t = t0 + blockIdx.y;
  const int rs = lane >> 2;
  const int c16 = (((lane & 3) ^ ((lane >> 3) & 3))) * 16;
  const int rdslot = ((lane >> 4) ^ ((lane >> 1) & 3)) * 8;

  f32x4 acc[4];
#pragma unroll
  for (int n = 0; n < 4; ++n) acc[n] = {0.f, 0.f, 0.f, 0.f};

  for (int kk = 0; kk < H_ / 32; ++kk) {
    const int k0 = kk * 32;
    __syncthreads();
    {
      int row = bx * 64 + wave * 16 + rs;
      gload_lds16((const char*)h + ((size_t)row * H_ + k0) * 2 + c16,
                  (char*)As + wave * 1024);
    }
    {
      int jj = wave * 16 + rs;
      gload_lds16((const char*)w1 + ((size_t)jj * H_ + k0) * 2 + c16,
                  (char*)Bs + wave * 1024);
    }
    __syncthreads();
    bf16x8 a = *(const bf16x8*)&As[(wave * 16 + (lane & 15)) * 32 + rdslot];
#pragma unroll
    for (int n = 0; n < 4; ++n) {
      bf16x8 b = *(const bf16x8*)&Bs[(n * 16 + (lane & 15)) * 32 + rdslot];
      acc[n] = __builtin_amdgcn_mfma_f32_16x16x32_bf16(a, b, acc[n], 0, 0, 0);
    }
  }

  const int r0 = (lane >> 4) * 4, cl = lane & 15;
#pragma unroll
  for (int n = 0; n < 4; ++n)
#pragma unroll
    for (int j = 0; j < 4; ++j) {
      int row = wave * 16 + r0 + j;     // local row 0..63
      int col = n * 16 + cl;            // hidden unit 0..63
      hid[row][col] = fmaxf(acc[n][j] + b1[col], 0.0f);
    }
  __syncthreads();

  if (tid < 128) {
    int r = tid >> 1, d = tid & 1;
    float s = b2[d];
#pragma unroll 8
    for (int k2 = 0; k2 < 64; ++k2) s += hid[r][k2] * w2[d * 64 + k2];
    delta[((size_t)(bx * 64 + r) * T_ + t) * 2 + d] = s;
  }
}

// ---------------- final cumsum over T + last_pos ----------------

__global__ void k_cumsum(const float* __restrict__ delta,
                         const float* __restrict__ lp, float* __restrict__ out) {
  int id = blockIdx.x * blockDim.x + threadIdx.x;
  if (id >= B_ * 2) return;
  int b = id >> 1, d = id & 1;
  float cum = lp[b * 2 + d];
  size_t base = (size_t)b * T_ * 2 + d;
  for (int t = 0; t < T_; ++t) {
    cum += delta[base + t * 2];
    out[base + t * 2] = cum;
  }
}

// ---------------- launch ----------------

extern "C" void kernel_launch(void* const* d_in, const int* in_sizes, int n_in,
                              void* d_out, int out_size, void* d_ws, size_t ws_size,
                              hipStream_t stream) {
  const float* z   = (const float*)d_in[0];
  const float* lv  = (const float*)d_in[1];
  const float* lp  = (const float*)d_in[2];
  const float* Wih = (const float*)d_in[3];
  const float* Whh = (const float*)d_in[4];
  const float* bih = (const float*)d_in[5];
  const float* bhh = (const float*)d_in[6];
  const float* W1  = (const float*)d_in[7];
  const float* b1  = (const float*)d_in[8];
  const float* W2  = (const float*)d_in[9];
  const float* b2  = (const float*)d_in[10];
  float* out = (float*)d_out;

  char* ws = (char*)d_ws;
  size_t off = 0;
  u16x4*          xg4    = (u16x4*)(ws + off);          off += (size_t)B_ * H_ * 8;       // 33554432
  unsigned short* whh_bf = (unsigned short*)(ws + off); off += (size_t)G4_ * H_ * 2;      //  8388608
  unsigned short* wih_bf = (unsigned short*)(ws + off); off += (size_t)G4_ * KA_ * 2;     //  8650752
  unsigned short* zaug   = (unsigned short*)(ws + off); off += (size_t)B_ * KA_ * 2;      //  8650752
  unsigned short* w1_bf  = (unsigned short*)(ws + off); off += (size_t)MLPH_ * H_ * 2;    //   131072
  unsigned short* hring  = (unsigned short*)(ws + off); off += (size_t)NB_ * B_ * H_ * 2; // 50331648
  float*          cbuf   = (float*)(ws + off);          off += (size_t)B_ * H_ * 4;       // 16777216
  float*          delta  = (float*)(ws + off);          off += (size_t)B_ * T_ * 2 * 4;   //  1966080
  // total 128450560 bytes

  const size_t BH = (size_t)B_ * H_;

  // zero c and the h(-1) slot (= slot NB_-1 of the ring)
  hipMemsetAsync(hring + (NB_ - 1) * BH, 0, BH * 2, stream);
  hipMemsetAsync(cbuf, 0, BH * 4, stream);

  k_conv_bf16 <<<2048, 256, 0, stream>>>(Whh, whh_bf, G4_ * H_);
  k_conv_wih  <<<2048, 256, 0, stream>>>(Wih, wih_bf);
  k_build_zaug<<<2048, 256, 0, stream>>>(z, lp, lv, zaug);
  k_conv_bf16 <<<256, 256, 0, stream>>>(W1, w1_bf, MLPH_ * H_);

  k_xgates<<<dim3(32, 32), 256, 0, stream>>>(zaug, wih_bf, bih, bhh, xg4);

  for (int t = 0; t < T_; ++t) {
    const unsigned short* hp = hring + (size_t)((t + NB_ - 1) % NB_) * BH;
    unsigned short*       hc = hring + (size_t)(t % NB_) * BH;
    k_step<<<dim3(32, 32), 256, 0, stream>>>(hp, whh_bf, xg4, cbuf, hc);
    if ((t % NB_) == NB_ - 1)
      k_mlp<<<dim3(64, NB_), 256, 0, stream>>>(hring, w1_bf, b1, W2, b2, delta, t - (NB_ - 1));
  }

  k_cumsum<<<32, 256, 0, stream>>>(delta, lp, out);
}

// Round 6
// 3045.209 us; speedup vs baseline: 1.2653x; 1.2653x over previous
//
#include <hip/hip_runtime.h>
#include <stdint.h>

#define B_    4096
#define H_    1024
#define T_    60
#define IN_   1028
#define KA_   1056      // IN_ padded to multiple of 32
#define G4_   4096      // 4*H
#define MLPH_ 64
#define NB_   6         // MLP batch depth / h ring size

typedef __attribute__((ext_vector_type(8))) short bf16x8;
typedef __attribute__((ext_vector_type(4))) float f32x4;
typedef __attribute__((ext_vector_type(4))) unsigned short u16x4;

#define GLOBAL_AS __attribute__((address_space(1)))
#define LDS_AS    __attribute__((address_space(3)))

__device__ __forceinline__ void gload_lds16(const void* g, void* l) {
  __builtin_amdgcn_global_load_lds((GLOBAL_AS void*)const_cast<void*>(g),
                                   (LDS_AS void*)l, 16, 0, 0);
}

__device__ __forceinline__ unsigned short f2bf(float f) {
  union { float f; unsigned int u; } v; v.f = f;
  unsigned int r = v.u + 0x7FFFu + ((v.u >> 16) & 1u);
  return (unsigned short)(r >> 16);
}

__device__ __forceinline__ float bf2f(unsigned short u) {
  union { unsigned int u; float f; } v; v.u = ((unsigned int)u) << 16;
  return v.f;
}

__device__ __forceinline__ float sigmf(float x) {
  float e = __expf(-x);
  return __builtin_amdgcn_rcpf(1.0f + e);
}

__device__ __forceinline__ float tanh_fast(float x) {
  x = fminf(fmaxf(x, -15.0f), 15.0f);
  float e = __expf(2.0f * x);
  return (e - 1.0f) * __builtin_amdgcn_rcpf(e + 1.0f);
}

// ---------------- conversion / setup kernels ----------------

__global__ void k_conv_bf16(const float* __restrict__ src,
                            unsigned short* __restrict__ dst, int n) {
  int i = blockIdx.x * blockDim.x + threadIdx.x;
  int stride = gridDim.x * blockDim.x;
  for (; i < n; i += stride) dst[i] = f2bf(src[i]);
}

// W_ih (4096 x 1028) -> bf16 padded (4096 x 1056)
__global__ void k_conv_wih(const float* __restrict__ w,
                           unsigned short* __restrict__ dst) {
  int i = blockIdx.x * blockDim.x + threadIdx.x;
  int stride = gridDim.x * blockDim.x;
  const int n = G4_ * KA_;
  for (; i < n; i += stride) {
    int r = i / KA_, k = i - r * KA_;
    dst[i] = (k < IN_) ? f2bf(w[(size_t)r * IN_ + k]) : (unsigned short)0;
  }
}

// z_aug = [z | last_pos | last_vel | zero-pad]  (4096 x 1056 bf16)
__global__ void k_build_zaug(const float* __restrict__ z,
                             const float* __restrict__ lp,
                             const float* __restrict__ lv,
                             unsigned short* __restrict__ dst) {
  int i = blockIdx.x * blockDim.x + threadIdx.x;
  int stride = gridDim.x * blockDim.x;
  const int n = B_ * KA_;
  for (; i < n; i += stride) {
    int b = i / KA_, k = i - b * KA_;
    float v;
    if (k < H_)            v = z[(size_t)b * H_ + k];
    else if (k < H_ + 2)   v = lp[b * 2 + (k - H_)];
    else if (k < IN_)      v = lv[b * 2 + (k - H_ - 2)];
    else                   v = 0.0f;
    dst[i] = f2bf(v);
  }
}

// ---------------- x_gates GEMM -> interleaved bf16x4 per (b, hc) ----------------
// round-4 structure (runs once, not hot). 16-row x 64B chunks, involution swizzle.

__global__ __launch_bounds__(256, 4) void k_xgates(
    const unsigned short* __restrict__ zaug, const unsigned short* __restrict__ wih,
    const float* __restrict__ bih, const float* __restrict__ bhh,
    u16x4* __restrict__ xg4) {
  __shared__ unsigned short As[2][128 * 32];
  __shared__ unsigned short Bs[2][128 * 32];
  const int tid = threadIdx.x, lane = tid & 63, wave = tid >> 6;
  const int bx = blockIdx.x, by = blockIdx.y;
  const int wm = wave >> 1, wn = wave & 1;
  const int rs = lane >> 2;
  const int c16 = (((lane & 3) ^ ((lane >> 3) & 3))) * 16;
  const int rdslot = ((lane >> 4) ^ ((lane >> 1) & 3)) * 8;

  const char* asrc0 = (const char*)zaug + ((size_t)(bx * 128 + (wave * 2 + 0) * 16 + rs) * KA_) * 2 + c16;
  const char* asrc1 = (const char*)zaug + ((size_t)(bx * 128 + (wave * 2 + 1) * 16 + rs) * KA_) * 2 + c16;
  const char* bsrc0 = (const char*)wih  + ((size_t)(wave * H_ + by * 32 +  0 + rs) * KA_) * 2 + c16;
  const char* bsrc1 = (const char*)wih  + ((size_t)(wave * H_ + by * 32 + 16 + rs) * KA_) * 2 + c16;

  f32x4 acc[4][4];   // [gate][m]
#pragma unroll
  for (int g = 0; g < 4; ++g)
#pragma unroll
    for (int m = 0; m < 4; ++m) acc[g][m] = {0.f, 0.f, 0.f, 0.f};

  gload_lds16(asrc0, &As[0][(wave * 2 + 0) * 512]);
  gload_lds16(asrc1, &As[0][(wave * 2 + 1) * 512]);
  gload_lds16(bsrc0, &Bs[0][(wave * 2 + 0) * 512]);
  gload_lds16(bsrc1, &Bs[0][(wave * 2 + 1) * 512]);
  __syncthreads();

  const int nt = KA_ / 32;
  int cur = 0;
  for (int kk = 0; kk < nt; ++kk) {
    if (kk + 1 < nt) {
      const size_t kb = (size_t)(kk + 1) * 64;
      gload_lds16(asrc0 + kb, &As[cur ^ 1][(wave * 2 + 0) * 512]);
      gload_lds16(asrc1 + kb, &As[cur ^ 1][(wave * 2 + 1) * 512]);
      gload_lds16(bsrc0 + kb, &Bs[cur ^ 1][(wave * 2 + 0) * 512]);
      gload_lds16(bsrc1 + kb, &Bs[cur ^ 1][(wave * 2 + 1) * 512]);
    }
    bf16x8 a[4], b[4];
#pragma unroll
    for (int m = 0; m < 4; ++m)
      a[m] = *(const bf16x8*)&As[cur][(wm * 64 + m * 16 + (lane & 15)) * 32 + rdslot];
#pragma unroll
    for (int g = 0; g < 4; ++g)
      b[g] = *(const bf16x8*)&Bs[cur][((g * 2 + wn) * 16 + (lane & 15)) * 32 + rdslot];
#pragma unroll
    for (int g = 0; g < 4; ++g)
#pragma unroll
      for (int m = 0; m < 4; ++m)
        acc[g][m] = __builtin_amdgcn_mfma_f32_16x16x32_bf16(a[m], b[g], acc[g][m], 0, 0, 0);
    __syncthreads();
    cur ^= 1;
  }

  const int r0 = (lane >> 4) * 4, cl = lane & 15;
  const int hc = by * 32 + wn * 16 + cl;
  const float bi = bih[hc]        + bhh[hc];
  const float bf = bih[1024 + hc] + bhh[1024 + hc];
  const float bg = bih[2048 + hc] + bhh[2048 + hc];
  const float bo = bih[3072 + hc] + bhh[3072 + hc];
#pragma unroll
  for (int m = 0; m < 4; ++m)
#pragma unroll
    for (int j = 0; j < 4; ++j) {
      int row = bx * 128 + wm * 64 + m * 16 + r0 + j;
      u16x4 st = {f2bf(acc[0][m][j] + bi), f2bf(acc[1][m][j] + bf),
                  f2bf(acc[2][m][j] + bg), f2bf(acc[3][m][j] + bo)};
      xg4[(size_t)row * H_ + hc] = st;
    }
}

// ---------------- LSTM step: 256-row 8-wave 2-phase-per-tile pipeline ----------------
// BM=256 rows, BN=64 hc x 4 gates (256 N-cols), BK=32, 16x16 grid, 512 thr.
// Per wave (wm=wave>>2, wn=wave&3): 128 rows x 16 hc x 4 gates -> acc[4][8].
// LDS: A[2][256x32], B[2][256x32] = 64 KB. Swizzle: 64B rows of 4x16B slots,
// phys slot = logical ^ (row&3); write-side via pre-swizzled global source.
// Ledger (per wave, 4 gloads/tile): prologue T0+T1 = 8 out.
//   kt=0: vmcnt(4). kt=1..30: ph0 stage 2(A of kt+1) -> vmcnt(2); ph1 stage 2(B).
//   kt=31: vmcnt(0). Counted vmcnt never drains mid-loop (T4).

#define SBAR() asm volatile("s_barrier" ::: "memory")

#define MFMA_HALF(MB)                                                          \
  _Pragma("unroll") for (int g = 0; g < 4; ++g)                                \
  _Pragma("unroll") for (int m = 0; m < 4; ++m)                                \
      acc[g][(MB) + m] = __builtin_amdgcn_mfma_f32_16x16x32_bf16(              \
          a[m], b[g], acc[g][(MB) + m], 0, 0, 0);

#define TILE_BODY(KT, VMS, STG)                                                \
  {                                                                            \
    const int c_ = (KT) & 1;                                                   \
    if (STG) { stageA((KT) + 1, c_ ^ 1, 0); stageA((KT) + 1, c_ ^ 1, 1); }     \
    asm volatile("s_waitcnt vmcnt(" VMS ")" ::: "memory");                     \
    SBAR();                                                                    \
    rdA(c_, 0); rdB(c_);                                                       \
    __builtin_amdgcn_s_setprio(1);                                             \
    MFMA_HALF(0)                                                               \
    __builtin_amdgcn_s_setprio(0);                                             \
    SBAR();                                                                    \
    rdA(c_, 1);                                                                \
    if (STG) { stageB((KT) + 1, c_ ^ 1, 0); stageB((KT) + 1, c_ ^ 1, 1); }     \
    SBAR();                                                                    \
    __builtin_amdgcn_s_setprio(1);                                             \
    MFMA_HALF(4)                                                               \
    __builtin_amdgcn_s_setprio(0);                                             \
    SBAR();                                                                    \
  }

__global__ __launch_bounds__(512, 2) void k_step(
    const unsigned short* __restrict__ hprev, const unsigned short* __restrict__ whh,
    const u16x4* __restrict__ xg4, float* __restrict__ cbuf,
    unsigned short* __restrict__ hout) {
  __shared__ unsigned short As[2][256 * 32];
  __shared__ unsigned short Bs[2][256 * 32];
  const int tid = threadIdx.x, lane = tid & 63, wave = tid >> 6;
  const int bx = blockIdx.x, by = blockIdx.y;
  const int wm = wave >> 2, wn = wave & 3;
  const int cl = lane & 15, sl16 = lane >> 4;

  // staging: op covers 128 rows; thread t -> row o*128 + (t>>2), slot t&3.
  // pre-swizzled source slot = (lane&3) ^ ((lane>>2)&3)  [(row&3) == (lane>>2)&3]
  const int ssrc = (lane & 3) ^ ((lane >> 2) & 3);
  const char* aglb = (const char*)hprev +
      ((size_t)(bx * 256 + wave * 16 + (lane >> 2)) * H_) * 2 + ssrc * 16;
  // B rows are gate-cols: n = o*128 + wave*16 + (lane>>2); g = (o*2 + (wave>>2));
  const int bn_lo = by * 64 + (wave & 3) * 16 + (lane >> 2);
  const char* bglb = (const char*)whh + ((size_t)bn_lo * H_) * 2 + ssrc * 16;
  const size_t bg_off = ((size_t)(wave >> 2) * 1024) * H_ * 2;  // within-op gate

  auto stageA = [&](int kt, int c, int o) {
    gload_lds16(aglb + (size_t)o * 128 * H_ * 2 + (size_t)kt * 64,
                (char*)&As[c][0] + o * 8192 + wave * 1024);
  };
  auto stageB = [&](int kt, int c, int o) {
    gload_lds16(bglb + bg_off + (size_t)o * 2048 * H_ * 2 + (size_t)kt * 64,
                (char*)&Bs[c][0] + o * 8192 + wave * 1024);
  };

  // fragment reads: row*32 elems, phys slot = sl16 ^ (row&3), row&3 = cl&3
  const int offk = (sl16 ^ (cl & 3)) * 8;
  const int base_a = (wm * 128 + cl) * 32;
  const int base_b = (wn * 16 + cl) * 32;

  f32x4 acc[4][8];
#pragma unroll
  for (int g = 0; g < 4; ++g)
#pragma unroll
    for (int m = 0; m < 8; ++m) acc[g][m] = {0.f, 0.f, 0.f, 0.f};

  bf16x8 a[4], b[4];
  auto rdA = [&](int c, int mh) {
#pragma unroll
    for (int m = 0; m < 4; ++m)
      a[m] = *(const bf16x8*)&As[c][base_a + (mh * 4 + m) * 512 + offk];
  };
  auto rdB = [&](int c) {
#pragma unroll
    for (int g = 0; g < 4; ++g)
      b[g] = *(const bf16x8*)&Bs[c][base_b + g * 2048 + offk];
  };

  // prologue: tiles 0 (buf0) and 1 (buf1), 8 loads in flight
  stageA(0, 0, 0); stageA(0, 0, 1); stageB(0, 0, 0); stageB(0, 0, 1);
  stageA(1, 1, 0); stageA(1, 1, 1); stageB(1, 1, 0); stageB(1, 1, 1);

  TILE_BODY(0, "4", false)
  for (int kt = 1; kt <= 30; ++kt) {
    TILE_BODY(kt, "2", true)
  }
  TILE_BODY(31, "0", false)

  // epilogue: 32 outputs/lane
  const int erow0 = bx * 256 + wm * 128 + sl16 * 4;
  const int hc = by * 64 + wn * 16 + cl;
#pragma unroll
  for (int m = 0; m < 8; ++m)
#pragma unroll
    for (int j = 0; j < 4; ++j) {
      size_t ci = (size_t)(erow0 + m * 16 + j) * H_ + hc;
      u16x4 xv = xg4[ci];
      float iv = sigmf(acc[0][m][j] + bf2f(xv[0]));
      float fv = sigmf(acc[1][m][j] + bf2f(xv[1]));
      float gv = tanh_fast(acc[2][m][j] + bf2f(xv[2]));
      float ov = sigmf(acc[3][m][j] + bf2f(xv[3]));
      float cv = fv * cbuf[ci] + iv * gv;
      cbuf[ci] = cv;
      hout[ci] = f2bf(ov * tanh_fast(cv));
    }
}

// ---------------- batched MLP over NB_ steps ----------------

__global__ __launch_bounds__(256) void k_mlp(
    const unsigned short* __restrict__ hring, const unsigned short* __restrict__ w1,
    const float* __restrict__ b1, const float* __restrict__ w2,
    const float* __restrict__ b2, float* __restrict__ delta, int t0) {
  __shared__ unsigned short As[64 * 32];
  __shared__ unsigned short Bs[64 * 32];
  __shared__ float hid[64][65];
  const int tid = threadIdx.x, lane = tid & 63, wave = tid >> 6;
  const int bx = blockIdx.x;
  const unsigned short* h = hring + (size_t)blockIdx.y * B_ * H_;
  const int t = t0 + blockIdx.y;
  const int rs = lane >> 2;
  const int c16 = (((lane & 3) ^ ((lane >> 3) & 3))) * 16;
  const int rdslot = ((lane >> 4) ^ ((lane >> 1) & 3)) * 8;

  f32x4 acc[4];
#pragma unroll
  for (int n = 0; n < 4; ++n) acc[n] = {0.f, 0.f, 0.f, 0.f};

  for (int kk = 0; kk < H_ / 32; ++kk) {
    const int k0 = kk * 32;
    __syncthreads();
    {
      int row = bx * 64 + wave * 16 + rs;
      gload_lds16((const char*)h + ((size_t)row * H_ + k0) * 2 + c16,
                  (char*)As + wave * 1024);
    }
    {
      int jj = wave * 16 + rs;
      gload_lds16((const char*)w1 + ((size_t)jj * H_ + k0) * 2 + c16,
                  (char*)Bs + wave * 1024);
    }
    __syncthreads();
    bf16x8 a = *(const bf16x8*)&As[(wave * 16 + (lane & 15)) * 32 + rdslot];
#pragma unroll
    for (int n = 0; n < 4; ++n) {
      bf16x8 b = *(const bf16x8*)&Bs[(n * 16 + (lane & 15)) * 32 + rdslot];
      acc[n] = __builtin_amdgcn_mfma_f32_16x16x32_bf16(a, b, acc[n], 0, 0, 0);
    }
  }

  const int r0 = (lane >> 4) * 4, cl = lane & 15;
#pragma unroll
  for (int n = 0; n < 4; ++n)
#pragma unroll
    for (int j = 0; j < 4; ++j) {
      int row = wave * 16 + r0 + j;     // local row 0..63
      int col = n * 16 + cl;            // hidden unit 0..63
      hid[row][col] = fmaxf(acc[n][j] + b1[col], 0.0f);
    }
  __syncthreads();

  if (tid < 128) {
    int r = tid >> 1, d = tid & 1;
    float s = b2[d];
#pragma unroll 8
    for (int k2 = 0; k2 < 64; ++k2) s += hid[r][k2] * w2[d * 64 + k2];
    delta[((size_t)(bx * 64 + r) * T_ + t) * 2 + d] = s;
  }
}

// ---------------- final cumsum over T + last_pos ----------------

__global__ void k_cumsum(const float* __restrict__ delta,
                         const float* __restrict__ lp, float* __restrict__ out) {
  int id = blockIdx.x * blockDim.x + threadIdx.x;
  if (id >= B_ * 2) return;
  int b = id >> 1, d = id & 1;
  float cum = lp[b * 2 + d];
  size_t base = (size_t)b * T_ * 2 + d;
  for (int t = 0; t < T_; ++t) {
    cum += delta[base + t * 2];
    out[base + t * 2] = cum;
  }
}

// ---------------- launch ----------------

extern "C" void kernel_launch(void* const* d_in, const int* in_sizes, int n_in,
                              void* d_out, int out_size, void* d_ws, size_t ws_size,
                              hipStream_t stream) {
  const float* z   = (const float*)d_in[0];
  const float* lv  = (const float*)d_in[1];
  const float* lp  = (const float*)d_in[2];
  const float* Wih = (const float*)d_in[3];
  const float* Whh = (const float*)d_in[4];
  const float* bih = (const float*)d_in[5];
  const float* bhh = (const float*)d_in[6];
  const float* W1  = (const float*)d_in[7];
  const float* b1  = (const float*)d_in[8];
  const float* W2  = (const float*)d_in[9];
  const float* b2  = (const float*)d_in[10];
  float* out = (float*)d_out;

  char* ws = (char*)d_ws;
  size_t off = 0;
  u16x4*          xg4    = (u16x4*)(ws + off);          off += (size_t)B_ * H_ * 8;       // 33554432
  unsigned short* whh_bf = (unsigned short*)(ws + off); off += (size_t)G4_ * H_ * 2;      //  8388608
  unsigned short* wih_bf = (unsigned short*)(ws + off); off += (size_t)G4_ * KA_ * 2;     //  8650752
  unsigned short* zaug   = (unsigned short*)(ws + off); off += (size_t)B_ * KA_ * 2;      //  8650752
  unsigned short* w1_bf  = (unsigned short*)(ws + off); off += (size_t)MLPH_ * H_ * 2;    //   131072
  unsigned short* hring  = (unsigned short*)(ws + off); off += (size_t)NB_ * B_ * H_ * 2; // 50331648
  float*          cbuf   = (float*)(ws + off);          off += (size_t)B_ * H_ * 4;       // 16777216
  float*          delta  = (float*)(ws + off);          off += (size_t)B_ * T_ * 2 * 4;   //  1966080
  // total 128450560 bytes

  const size_t BH = (size_t)B_ * H_;

  // zero c and the h(-1) slot (= slot NB_-1 of the ring)
  hipMemsetAsync(hring + (NB_ - 1) * BH, 0, BH * 2, stream);
  hipMemsetAsync(cbuf, 0, BH * 4, stream);

  k_conv_bf16 <<<2048, 256, 0, stream>>>(Whh, whh_bf, G4_ * H_);
  k_conv_wih  <<<2048, 256, 0, stream>>>(Wih, wih_bf);
  k_build_zaug<<<2048, 256, 0, stream>>>(z, lp, lv, zaug);
  k_conv_bf16 <<<256, 256, 0, stream>>>(W1, w1_bf, MLPH_ * H_);

  k_xgates<<<dim3(32, 32), 256, 0, stream>>>(zaug, wih_bf, bih, bhh, xg4);

  for (int t = 0; t < T_; ++t) {
    const unsigned short* hp = hring + (size_t)((t + NB_ - 1) % NB_) * BH;
    unsigned short*       hc = hring + (size_t)(t % NB_) * BH;
    k_step<<<dim3(16, 16), 512, 0, stream>>>(hp, whh_bf, xg4, cbuf, hc);
    if ((t % NB_) == NB_ - 1)
      k_mlp<<<dim3(64, NB_), 256, 0, stream>>>(hring, w1_bf, b1, W2, b2, delta, t - (NB_ - 1));
  }

  k_cumsum<<<32, 256, 0, stream>>>(delta, lp, out);
}